// Round 13
// baseline (109.760 us; speedup 1.0000x reference)
//
#include <hip/hip_runtime.h>
#include <hip/hip_bf16.h>

// MACE-like GNN on MI355X — MFMA both GEMMs, swapped-operand B+C (D[f][j])
// so packed-f32 consume works against round-10's coalesced layouts.
// B=32, N=128, F=64, N_RBF=8, H_R=64, L=2.
// s: [B][N][F] (unchanged).  v: [B][N][3][F] (d-major rows, f contiguous).

#define NN 128
#define BB 32
#define FF 64

using f32x4  = __attribute__((ext_vector_type(4))) float;
using short8 = __attribute__((ext_vector_type(8))) short;
using half4  = __attribute__((ext_vector_type(4))) _Float16;

__device__ __forceinline__ unsigned short f2bf(float x) {
    unsigned int u = __float_as_uint(x);
    u += 0x7fff + ((u >> 16) & 1);          // RNE
    return (unsigned short)(u >> 16);
}
__device__ __forceinline__ unsigned int f2bf_fast32(float x) {
    return (__float_as_uint(x) + 0x8000u) >> 16;
}
__device__ __forceinline__ f32x4 shfl_xor4(f32x4 v, int m) {
    f32x4 r;
    r[0] = __shfl_xor(v[0], m, 64);
    r[1] = __shfl_xor(v[1], m, 64);
    r[2] = __shfl_xor(v[2], m, 64);
    r[3] = __shfl_xor(v[3], m, 64);
    return r;
}

// -------------------- setup: bake weights + init node scalars --------------
__global__ __launch_bounds__(256) void setup_kernel(
    const float* __restrict__ w2,     // [2][64][192]
    const float* __restrict__ ws,     // [2][64][64]
    const float* __restrict__ wv,     // [2][64][64]
    const float* __restrict__ rbf_w1, // [2][8][64]
    const float* __restrict__ rbf_b1, // [2][64]
    const int* __restrict__ species, const float* __restrict__ glob,
    const float* __restrict__ embed, const float* __restrict__ glob_w,
    short* __restrict__ w2frag,       // [2][4][3][2][64][8] = 24576 shorts
    float* __restrict__ wT4,          // [2][2][16][64][4]   = 16384 floats
    _Float16* __restrict__ w1A,       // [2][4][64][4]       = 2048 halfs
    float* __restrict__ s)            // [B][N][F]
{
    const int blk = blockIdx.x;
    if (blk < 192) {
        const int tid = blk * 256 + threadIdx.x;
        const int NFRAG = 24576;
        if (tid < NFRAG) {
            // frag (A or B, same lane map): lane holds M[k=(l>>4)*8+e][idx=l&15]
            const int e  = tid & 7;
            const int l  = (tid >> 3) & 63;
            const int ks = (tid >> 9) & 1;
            const int q  = tid >> 10;          // layer*12 + wave*3 + nt
            const int nt = q % 3;
            const int wv_ = (q / 3) & 3;
            const int layer = q / 12;
            const int col = nt * 64 + wv_ * 16 + (l & 15);
            const int hb  = ks * 32 + (l >> 4) * 8 + e;
            const float val = w2[layer * 64 * 192 + hb * 192 + col] * (1.0f / 127.0f);
            w2frag[tid] = (short)f2bf(val);
        }
        const int tid2 = tid - NFRAG;
        if (tid2 >= 0 && tid2 < 16384) {
            const int c   = tid2 & 3;
            const int g   = (tid2 >> 2) & 63;
            const int ff4 = (tid2 >> 8) & 15;
            const int m   = (tid2 >> 12) & 1;
            const int layer = tid2 >> 13;
            const float* src = (m == 0 ? ws : wv) + layer * 4096;
            wT4[tid2] = src[(ff4 * 4 + c) * 64 + g];
        }
        const int tid3 = tid - NFRAG - 16384;
        if (tid3 >= 0 && tid3 < 2048) {
            // A-frag 16x16x16: lane l holds A[row=l&15][k=(l>>4)*4+e]
            const int e  = tid3 & 3;
            const int l  = (tid3 >> 2) & 63;
            const int wv_ = (tid3 >> 8) & 3;
            const int layer = tid3 >> 10;
            const int k = (l >> 4) * 4 + e;
            const int h = wv_ * 16 + (l & 15);
            float val = 0.0f;
            if (k < 8)       val = rbf_w1[layer * 512 + k * 64 + h];
            else if (k == 8) val = rbf_b1[layer * 64 + h];
            w1A[tid3] = (_Float16)val;
        }
    } else {
        const int node = (blk - 192) * 4 + (threadIdx.x >> 6);   // b*128 + n
        const int b = node >> 7;
        const int f = threadIdx.x & 63;
        const int sp = species[node];
        float acc = embed[sp * FF + f];
#pragma unroll
        for (int k = 0; k < 16; ++k)
            acc = fmaf(glob[b * 16 + k], glob_w[k * FF + f], acc);
        s[node * FF + f] = acc;
    }
}

// -------------------- fused message+agg+update (+readout for LAYER==1) ----
// grid 4096 (XCD-swizzled), block 256 = 4 waves; wave w owns f in [16w,16w+16).
template<int LAYER>
__global__ __launch_bounds__(256, 4) void msg_kernel(
    const float* __restrict__ pos,     // [B][N][3]
    const float* __restrict__ s_in,    // [B][N][F]
    const float* __restrict__ v_in,    // [B][N][3][F] (unused when LAYER==0)
    const half4* __restrict__ w1Abuf,  // [4][64] half4 (layer slice)
    const short* __restrict__ w2frag,  // [4][3][2][64][8] bf16 (layer slice)
    const float* __restrict__ wT4,     // [2][16][64][4] (ws,wv; layer slice)
    const float* __restrict__ wout,    // [64]
    const float* __restrict__ scale,   // [1]
    float* __restrict__ s_out,         // LAYER==0 only, [B][N][F]
    float* __restrict__ v_out,         // LAYER==0 only, [B][N][3][F]
    float* __restrict__ out)           // LAYER==1 only
{
    __shared__ unsigned short hid_lds[NN * 64];       // 16 KB, XOR-swizzled rows
    __shared__ float4 unit_lds[NN];                   // 2 KB
    __shared__ __align__(16) char phi_pool[NN * 32];  // 4 KB; agg4 aliases after A2
    f32x4 (*agg4)[16] = (f32x4(*)[16])phi_pool;

    // XCD-aware swizzle: 4 consecutive batches per XCD -> L2-resident s/v.
    const int blk = blockIdx.x;
    const int xcd = blk & 7;
    const int idx = blk >> 3;            // 0..511
    const int b = xcd * 4 + (idx >> 7);
    const int i = idx & 127;

    const int t = threadIdx.x;
    const int w = t >> 6;          // wave
    const int l = t & 63;          // lane
    const float* pb = pos + b * NN * 3;

    // ---- fragments (W2), pre-baked; nt=1 (r2) unused in layer 0 ----
    short8 bfrag[3][2];
    {
        const short8* wf = (const short8*)w2frag;
#pragma unroll
        for (int nt = 0; nt < 3; ++nt) {
            if (LAYER == 0 && nt == 1) continue;
#pragma unroll
            for (int ks = 0; ks < 2; ++ks)
                bfrag[nt][ks] = wf[((w * 3 + nt) * 2 + ks) * 64 + l];
        }
    }

    // ---- phase A1: distance/unit + phi (f16 rows [128][16], K=16) ----
    {
        const int j = t & 127;
        const int half = t >> 7;
        const float dx = pb[i * 3 + 0] - pb[j * 3 + 0];
        const float dy = pb[i * 3 + 1] - pb[j * 3 + 1];
        const float dz = pb[i * 3 + 2] - pb[j * 3 + 2];
        const float d2 = fmaf(dx, dx, fmaf(dy, dy, fmaf(dz, dz, 1e-12f)));
        const float inv = __builtin_amdgcn_rsqf(d2);
        const float dd = d2 * inv;
        if (half == 0)
            unit_lds[j] = make_float4(dx * inv, dy * inv, dz * inv, 0.0f);
        const _Float16 zf = (_Float16)0.f;
        half4 ph;
#pragma unroll
        for (int r = 0; r < 4; ++r) {
            const float td = dd - (float)(half * 4 + r) * (5.0f / 7.0f);
            ph[r] = (_Float16)__expf(td * td * -1.28f);   // 1/(2*0.625^2)
        }
        if (j == i) ph = (half4){zf, zf, zf, zf};
        char* rowp = phi_pool + j * 32;
        const int swz = ((j >> 2) & 3) << 3;
        *(half4*)(rowp + ((half * 8) ^ swz)) = ph;
        if (half == 0) {
            half4 bias = {(j == i) ? zf : (_Float16)1.0f, zf, zf, zf};
            *(half4*)(rowp + (16 ^ swz)) = bias;          // k=8..11
        } else {
            *(half4*)(rowp + (24 ^ swz)) = (half4){zf, zf, zf, zf}; // k=12..15
        }
    }
    __syncthreads();

    // ---- phase A2: pre[h,j] = mfma(W1^T, phi^T); silu -> hid_lds (b64) ----
    {
        const half4 w1a = w1Abuf[w * 64 + l];
        const int jcol = l & 15;
        const int chunk = (l >> 4) * 8;
        const int hbyte = w * 32 + (l >> 4) * 8;   // h = w*16 + (l>>4)*4 + reg
#pragma unroll
        for (int mt = 0; mt < 8; ++mt) {
            const int j = mt * 16 + jcol;
            const half4 bphi = *(const half4*)(
                phi_pool + j * 32 + (chunk ^ (((j >> 2) & 3) << 3)));
            f32x4 pre = __builtin_amdgcn_mfma_f32_16x16x16f16(
                w1a, bphi, (f32x4){0.f, 0.f, 0.f, 0.f}, 0, 0, 0);
            unsigned int pk[2];
#pragma unroll
            for (int p = 0; p < 2; ++p) {
                float sv[2];
#pragma unroll
                for (int q = 0; q < 2; ++q) {
                    const float z = pre[p * 2 + q];
                    const float ex = __expf(-z);
                    sv[q] = z * __builtin_amdgcn_rcpf(1.0f + ex);
                }
                pk[p] = f2bf_fast32(sv[0]) | (f2bf_fast32(sv[1]) << 16);
            }
            const int byte = j * 128 + (hbyte ^ ((j & 7) << 4));
            *(uint2*)((char*)hid_lds + byte) = make_uint2(pk[0], pk[1]);
        }
    }
    __syncthreads();

    // ---- fused phase B+C, SWAPPED: D[row=f][col=j] ----
    // lane: j = mt*16 + (l&15), f0 = w*16 + (l>>4)*4 (4 consecutive f in regs).
    const int f0   = w * 16 + (l >> 4) * 4;
    const int jln  = l & 15;
    const float* sb = s_in + b * NN * FF;
    const float* vb = (LAYER > 0) ? (v_in + b * NN * 192) : nullptr;

    f32x4 accs4 = (f32x4){0.f, 0.f, 0.f, 0.f};
    f32x4 av04  = (f32x4){0.f, 0.f, 0.f, 0.f};
    f32x4 av14  = (f32x4){0.f, 0.f, 0.f, 0.f};
    f32x4 av24  = (f32x4){0.f, 0.f, 0.f, 0.f};

    // prefetch tile 0
    f32x4 sP = *(const f32x4*)(sb + jln * FF + f0);
    f32x4 vxP, vyP, vzP;
    if (LAYER > 0) {
        vxP = *(const f32x4*)(vb + jln * 192 +   0 + f0);
        vyP = *(const f32x4*)(vb + jln * 192 +  64 + f0);
        vzP = *(const f32x4*)(vb + jln * 192 + 128 + f0);
    }

#pragma unroll
    for (int mt = 0; mt < 8; ++mt) {
        const int j = mt * 16 + jln;
        const int base = j * 128;
        const int sw = (j & 7) << 4;
        const short8 h0 = *(const short8*)((const char*)hid_lds + base + (((l >> 4) * 16 +  0) ^ sw));
        const short8 h1 = *(const short8*)((const char*)hid_lds + base + (((l >> 4) * 16 + 64) ^ sw));

        f32x4 c0 = (f32x4){0.f, 0.f, 0.f, 0.f};
        f32x4 c1 = (f32x4){0.f, 0.f, 0.f, 0.f};
        f32x4 c2 = (f32x4){0.f, 0.f, 0.f, 0.f};
        c0 = __builtin_amdgcn_mfma_f32_16x16x32_bf16(bfrag[0][0], h0, c0, 0, 0, 0);
        c0 = __builtin_amdgcn_mfma_f32_16x16x32_bf16(bfrag[0][1], h1, c0, 0, 0, 0);
        if (LAYER > 0) {
            c1 = __builtin_amdgcn_mfma_f32_16x16x32_bf16(bfrag[1][0], h0, c1, 0, 0, 0);
            c1 = __builtin_amdgcn_mfma_f32_16x16x32_bf16(bfrag[1][1], h1, c1, 0, 0, 0);
        }
        c2 = __builtin_amdgcn_mfma_f32_16x16x32_bf16(bfrag[2][0], h0, c2, 0, 0, 0);
        c2 = __builtin_amdgcn_mfma_f32_16x16x32_bf16(bfrag[2][1], h1, c2, 0, 0, 0);

        // prefetch next tile while MFMAs are in flight
        f32x4 sN, vxN, vyN, vzN;
        if (mt < 7) {
            const int jn = j + 16;
            sN = *(const f32x4*)(sb + jn * FF + f0);
            if (LAYER > 0) {
                vxN = *(const f32x4*)(vb + jn * 192 +   0 + f0);
                vyN = *(const f32x4*)(vb + jn * 192 +  64 + f0);
                vzN = *(const f32x4*)(vb + jn * 192 + 128 + f0);
            }
        }

        // packed consume: acc lanes = 4 consecutive f, scalar u[j] broadcast
        const float4 u = unit_lds[j];
        accs4 = accs4 + c0 * sP;
        const f32x4 r3s = c2 * sP;
        av04 = av04 + r3s * u.x;
        av14 = av14 + r3s * u.y;
        av24 = av24 + r3s * u.z;
        if (LAYER > 0) {
            av04 = av04 + c1 * vxP;
            av14 = av14 + c1 * vyP;
            av24 = av24 + c1 * vzP;
        }

        sP = sN;
        if (LAYER > 0) { vxP = vxN; vyP = vyN; vzP = vzN; }
    }

    // reduce over j (lanes l&15), keep per-f vectors
#pragma unroll
    for (int m = 1; m < 16; m <<= 1) {
        accs4 = accs4 + shfl_xor4(accs4, m);
        av04  = av04  + shfl_xor4(av04, m);
        av14  = av14  + shfl_xor4(av14, m);
        av24  = av24  + shfl_xor4(av24, m);
    }
    if ((l & 15) == 0) {
        const int fi = w * 4 + (l >> 4);   // f0/4
        agg4[0][fi] = accs4;
        agg4[1][fi] = av04;
        agg4[2][fi] = av14;
        agg4[3][fi] = av24;
    }
    __syncthreads();

    // ---- tail: node update (+ readout), packed dot via wT4 [m][ff4][g][4] --
    const int g = l;
    const int node = b * NN + i;
    const f32x4* wv4 = (const f32x4*)wT4;
    if (LAYER == 0) {
        const int m = (w == 0) ? 0 : 1;
        const int row = (w == 0) ? 0 : w;
        f32x4 a4 = (f32x4){0.f, 0.f, 0.f, 0.f};
#pragma unroll
        for (int k = 0; k < 16; ++k)
            a4 = a4 + wv4[(m * 16 + k) * 64 + g] * agg4[row][k];
        float a = (a4[0] + a4[1]) + (a4[2] + a4[3]);
        if (w == 0) {
            a += s_in[node * FF + g];
            s_out[node * FF + g] = a;
        } else {
            v_out[node * 192 + (w - 1) * 64 + g] = a;
        }
    } else {
        if (w > 0) {
            const int d = w - 1;
            f32x4 a4 = (f32x4){0.f, 0.f, 0.f, 0.f};
#pragma unroll
            for (int k = 0; k < 16; ++k)
                a4 = a4 + wv4[(16 + k) * 64 + g] * agg4[w][k];
            float a = (a4[0] + a4[1]) + (a4[2] + a4[3])
                    + v_in[node * 192 + d * 64 + g];
            float p = a * wout[g];
#pragma unroll
            for (int off = 1; off < 64; off <<= 1)
                p += __shfl_xor(p, off, 64);
            if (l == 0)
                out[node * 3 + d] = (p - pos[node * 3 + d]) * scale[0];
        }
    }
}

extern "C" void kernel_launch(void* const* d_in, const int* in_sizes, int n_in,
                              void* d_out, int out_size, void* d_ws, size_t ws_size,
                              hipStream_t stream) {
    const float* pos     = (const float*)d_in[0];
    const int*   species = (const int*)  d_in[1];
    const float* glob    = (const float*)d_in[2];
    const float* embed   = (const float*)d_in[3];
    const float* glob_w  = (const float*)d_in[4];
    const float* rbf_w1  = (const float*)d_in[5];   // [2][8][64]
    const float* rbf_b1  = (const float*)d_in[6];   // [2][64]
    const float* rbf_w2  = (const float*)d_in[7];   // [2][64][192]
    const float* ws      = (const float*)d_in[8];   // [2][64][64]
    const float* wv      = (const float*)d_in[9];   // [2][64][64]
    const float* wout    = (const float*)d_in[10];  // [64]
    const float* scale   = (const float*)d_in[11];  // [1]

    float* wsf = (float*)d_ws;
    float* s0     = wsf;                        // [B][N][F]    262144 floats
    float* s1     = wsf + 262144;               // [B][N][F]    262144
    float* v1     = wsf + 524288;               // [B][N][3][F] 786432
    short* w2frag = (short*)(wsf + 1310720);    // 24576 shorts (12288 floats)
    float* wT4    = wsf + 1323008;              // 16384 floats
    _Float16* w1A = (_Float16*)(wsf + 1339392); // 2048 halfs (1024 floats)
    float* outp = (float*)d_out;

    setup_kernel<<<dim3(192 + BB * NN / 4), 256, 0, stream>>>(
        rbf_w2, ws, wv, rbf_w1, rbf_b1, species, glob, embed, glob_w,
        w2frag, wT4, w1A, s0);

    msg_kernel<0><<<dim3(NN * BB), 256, 0, stream>>>(
        pos, s0, nullptr,
        (const half4*)w1A, w2frag, wT4, wout, scale,
        s1, v1, nullptr);

    msg_kernel<1><<<dim3(NN * BB), 256, 0, stream>>>(
        pos, s1, v1,
        (const half4*)(w1A + 1024), w2frag + 12288, wT4 + 8192, wout, scale,
        nullptr, nullptr, outp);
}

// Round 14
// 78.947 us; speedup vs baseline: 1.3903x; 1.3903x over previous
//
#include <hip/hip_runtime.h>
#include <hip/hip_bf16.h>

// MACE-like GNN on MI355X — MFMA for BOTH GEMMs.
// B=32, N=128, F=64, N_RBF=8, H_R=64, L=2.
// Round 14: EXACT round-10 kernel (best: 82.8us) with launch_bounds relaxed
// (256,4)->(256,2): LDS allows 7 blocks/CU, VGPR 52 fits the 128-cap with
// margin; rounds 12/13's packed-consume layouts reverted (16-segment gather).

#define NN 128
#define BB 32
#define FF 64

using f32x4  = __attribute__((ext_vector_type(4))) float;
using short8 = __attribute__((ext_vector_type(8))) short;
using half4  = __attribute__((ext_vector_type(4))) _Float16;

__device__ __forceinline__ unsigned short f2bf(float x) {
    unsigned int u = __float_as_uint(x);
    u += 0x7fff + ((u >> 16) & 1);          // RNE
    return (unsigned short)(u >> 16);
}
__device__ __forceinline__ unsigned int f2bf_fast32(float x) {
    return (__float_as_uint(x) + 0x8000u) >> 16;
}

// -------------------- setup: bake weights + init node scalars --------------
// blocks [0,192):    w2frag / wT4 / w1A bake
// blocks [192,1216): s0 = embed[species] + glob @ glob_w
__global__ __launch_bounds__(256) void setup_kernel(
    const float* __restrict__ w2,     // [2][64][192]
    const float* __restrict__ ws,     // [2][64][64]
    const float* __restrict__ wv,     // [2][64][64]
    const float* __restrict__ rbf_w1, // [2][8][64]
    const float* __restrict__ rbf_b1, // [2][64]
    const int* __restrict__ species, const float* __restrict__ glob,
    const float* __restrict__ embed, const float* __restrict__ glob_w,
    short* __restrict__ w2frag,       // [2][4][3][2][64][8] = 24576 shorts
    float* __restrict__ wT4,          // [2][2][16][64][4]   = 16384 floats
    _Float16* __restrict__ w1A,       // [2][4][64][4]       = 2048 halfs
    float* __restrict__ s)            // [B*N][64]
{
    const int blk = blockIdx.x;
    if (blk < 192) {
        const int tid = blk * 256 + threadIdx.x;
        const int NFRAG = 24576;
        if (tid < NFRAG) {
            const int e  = tid & 7;
            const int l  = (tid >> 3) & 63;
            const int ks = (tid >> 9) & 1;
            const int q  = tid >> 10;          // layer*12 + wave*3 + nt
            const int nt = q % 3;
            const int wv_ = (q / 3) & 3;
            const int layer = q / 12;
            const int col = nt * 64 + wv_ * 16 + (l & 15);
            const int hb  = ks * 32 + (l >> 4) * 8 + e;
            const float val = w2[layer * 64 * 192 + hb * 192 + col] * (1.0f / 127.0f);
            w2frag[tid] = (short)f2bf(val);
        }
        const int tid2 = tid - NFRAG;
        if (tid2 >= 0 && tid2 < 16384) {
            const int c   = tid2 & 3;
            const int g   = (tid2 >> 2) & 63;
            const int ff4 = (tid2 >> 8) & 15;
            const int m   = (tid2 >> 12) & 1;
            const int layer = tid2 >> 13;
            const float* src = (m == 0 ? ws : wv) + layer * 4096;
            wT4[tid2] = src[(ff4 * 4 + c) * 64 + g];
        }
        const int tid3 = tid - NFRAG - 16384;
        if (tid3 >= 0 && tid3 < 2048) {
            // A-frag 16x16x16: lane l holds A[row=l&15][k=(l>>4)*4+e]
            const int e  = tid3 & 3;
            const int l  = (tid3 >> 2) & 63;
            const int wv_ = (tid3 >> 8) & 3;
            const int layer = tid3 >> 10;
            const int k = (l >> 4) * 4 + e;
            const int h = wv_ * 16 + (l & 15);
            float val = 0.0f;
            if (k < 8)       val = rbf_w1[layer * 512 + k * 64 + h];
            else if (k == 8) val = rbf_b1[layer * 64 + h];
            w1A[tid3] = (_Float16)val;
        }
    } else {
        const int node = (blk - 192) * 4 + (threadIdx.x >> 6);   // b*128 + n
        const int b = node >> 7;
        const int f = threadIdx.x & 63;
        const int sp = species[node];
        float acc = embed[sp * FF + f];
#pragma unroll
        for (int k = 0; k < 16; ++k)
            acc = fmaf(glob[b * 16 + k], glob_w[k * FF + f], acc);
        s[node * FF + f] = acc;
    }
}

// -------------------- fused message+agg+update (+readout for LAYER==1) ----
// grid 4096 (XCD-swizzled), block 256 = 4 waves.
// wave w owns channels f in [16w, 16w+16).
template<int LAYER>
__global__ __launch_bounds__(256, 2) void msg_kernel(
    const float* __restrict__ pos,     // [B][N][3]
    const float* __restrict__ s_in,    // [B][N][F]
    const float* __restrict__ v_in,    // [B][N][F][4]  (unused when LAYER==0)
    const half4* __restrict__ w1Abuf,  // [4][64] half4 (layer slice)
    const short* __restrict__ w2frag,  // [4][3][2][64][8] bf16 (layer slice)
    const float* __restrict__ wT4,     // [2][16][64][4] (ws,wv; layer slice)
    const float* __restrict__ wout,    // [64]
    const float* __restrict__ scale,   // [1]
    float* __restrict__ s_out,         // LAYER==0 only
    float* __restrict__ v_out,         // LAYER==0 only, [B][N][F][4]
    float* __restrict__ out)           // LAYER==1 only
{
    __shared__ unsigned short hid_lds[NN * 64];       // 16 KB, XOR-swizzled rows
    __shared__ float4 unit_lds[NN];                   // 2 KB
    __shared__ __align__(16) char phi_pool[NN * 32];  // 4 KB; agg4 aliases after A2
    float4 (*agg4)[16] = (float4(*)[16])phi_pool;

    // XCD-aware swizzle: 4 consecutive batches per XCD -> L2-resident s/v.
    const int blk = blockIdx.x;
    const int xcd = blk & 7;
    const int idx = blk >> 3;            // 0..511
    const int b = xcd * 4 + (idx >> 7);
    const int i = idx & 127;

    const int t = threadIdx.x;
    const int w = t >> 6;          // wave
    const int l = t & 63;          // lane
    const int node = b * NN + i;
    const float* pb = pos + b * NN * 3;

    // ---- B fragments (W2), pre-baked; r2 frag unused in layer 0 ----
    short8 bfrag[3][2];
    {
        const short8* wf = (const short8*)w2frag;
#pragma unroll
        for (int nt = 0; nt < 3; ++nt) {
            if (LAYER == 0 && nt == 1) continue;
#pragma unroll
            for (int ks = 0; ks < 2; ++ks)
                bfrag[nt][ks] = wf[((w * 3 + nt) * 2 + ks) * 64 + l];
        }
    }

    // ---- phase A1: distance/unit + phi (f16 rows [128][16], K=16 layout) ---
    {
        const int j = t & 127;
        const int half = t >> 7;
        const float dx = pb[i * 3 + 0] - pb[j * 3 + 0];
        const float dy = pb[i * 3 + 1] - pb[j * 3 + 1];
        const float dz = pb[i * 3 + 2] - pb[j * 3 + 2];
        const float d2 = fmaf(dx, dx, fmaf(dy, dy, fmaf(dz, dz, 1e-12f)));
        const float inv = __builtin_amdgcn_rsqf(d2);
        const float dd = d2 * inv;
        if (half == 0)
            unit_lds[j] = make_float4(dx * inv, dy * inv, dz * inv, 0.0f);
        const _Float16 zf = (_Float16)0.f;
        half4 ph;
#pragma unroll
        for (int r = 0; r < 4; ++r) {
            const float td = dd - (float)(half * 4 + r) * (5.0f / 7.0f);
            ph[r] = (_Float16)__expf(td * td * -1.28f);   // 1/(2*0.625^2)
        }
        if (j == i) ph = (half4){zf, zf, zf, zf};
        char* rowp = phi_pool + j * 32;
        const int swz = ((j >> 2) & 3) << 3;
        *(half4*)(rowp + ((half * 8) ^ swz)) = ph;
        if (half == 0) {
            half4 bias = {(j == i) ? zf : (_Float16)1.0f, zf, zf, zf};
            *(half4*)(rowp + (16 ^ swz)) = bias;          // k=8..11
        } else {
            *(half4*)(rowp + (24 ^ swz)) = (half4){zf, zf, zf, zf}; // k=12..15
        }
    }
    __syncthreads();

    // ---- phase A2: pre[h,j] = mfma(W1^T, phi^T); silu -> hid_lds (b64) ----
    {
        const half4 w1a = w1Abuf[w * 64 + l];
        const int jcol = l & 15;
        const int chunk = (l >> 4) * 8;
        const int hbyte = w * 32 + (l >> 4) * 8;   // h = w*16 + (l>>4)*4 + reg
#pragma unroll
        for (int mt = 0; mt < 8; ++mt) {
            const int j = mt * 16 + jcol;
            const half4 bphi = *(const half4*)(
                phi_pool + j * 32 + (chunk ^ (((j >> 2) & 3) << 3)));
            f32x4 pre = __builtin_amdgcn_mfma_f32_16x16x16f16(
                w1a, bphi, (f32x4){0.f, 0.f, 0.f, 0.f}, 0, 0, 0);
            unsigned int pk[2];
#pragma unroll
            for (int p = 0; p < 2; ++p) {
                float sv[2];
#pragma unroll
                for (int q = 0; q < 2; ++q) {
                    const float z = pre[p * 2 + q];
                    const float ex = __expf(-z);
                    sv[q] = z * __builtin_amdgcn_rcpf(1.0f + ex);
                }
                pk[p] = f2bf_fast32(sv[0]) | (f2bf_fast32(sv[1]) << 16);
            }
            const int byte = j * 128 + (hbyte ^ ((j & 7) << 4));
            *(uint2*)((char*)hid_lds + byte) = make_uint2(pk[0], pk[1]);
        }
    }
    __syncthreads();

    // ---- fused phase B+C: per 16-row j-tile, MFMA then consume ----
    const int f    = w * 16 + (l & 15);
    const int jsub = (l >> 4) * 4;
    const float* sb = s_in + b * NN * FF;
    const float4* vb4 = (LAYER > 0) ? ((const float4*)v_in) + b * NN * FF : nullptr;

    float accs = 0.f, av0 = 0.f, av1 = 0.f, av2 = 0.f;

    float sP[4]; float4 vP[4];
#pragma unroll
    for (int reg = 0; reg < 4; ++reg) {
        const int j = jsub + reg;
        sP[reg] = sb[j * FF + f];
        if (LAYER > 0) vP[reg] = vb4[j * FF + f];
    }

#pragma unroll
    for (int mt = 0; mt < 8; ++mt) {
        const int jA = mt * 16 + (l & 15);
        const int base = jA * 128;
        const int sw = (jA & 7) << 4;
        const short8 a0 = *(const short8*)((const char*)hid_lds + base + (((l >> 4) * 16 +  0) ^ sw));
        const short8 a1 = *(const short8*)((const char*)hid_lds + base + (((l >> 4) * 16 + 64) ^ sw));

        f32x4 c0 = (f32x4){0.f, 0.f, 0.f, 0.f};
        f32x4 c1 = (f32x4){0.f, 0.f, 0.f, 0.f};
        f32x4 c2 = (f32x4){0.f, 0.f, 0.f, 0.f};
        c0 = __builtin_amdgcn_mfma_f32_16x16x32_bf16(a0, bfrag[0][0], c0, 0, 0, 0);
        c0 = __builtin_amdgcn_mfma_f32_16x16x32_bf16(a1, bfrag[0][1], c0, 0, 0, 0);
        if (LAYER > 0) {
            c1 = __builtin_amdgcn_mfma_f32_16x16x32_bf16(a0, bfrag[1][0], c1, 0, 0, 0);
            c1 = __builtin_amdgcn_mfma_f32_16x16x32_bf16(a1, bfrag[1][1], c1, 0, 0, 0);
        }
        c2 = __builtin_amdgcn_mfma_f32_16x16x32_bf16(a0, bfrag[2][0], c2, 0, 0, 0);
        c2 = __builtin_amdgcn_mfma_f32_16x16x32_bf16(a1, bfrag[2][1], c2, 0, 0, 0);

        float sN[4]; float4 vN[4];
        if (mt < 7) {
#pragma unroll
            for (int reg = 0; reg < 4; ++reg) {
                const int j = (mt + 1) * 16 + jsub + reg;
                sN[reg] = sb[j * FF + f];
                if (LAYER > 0) vN[reg] = vb4[j * FF + f];
            }
        }

#pragma unroll
        for (int reg = 0; reg < 4; ++reg) {
            const int j  = mt * 16 + jsub + reg;
            const float r1 = c0[reg];
            const float r2 = c1[reg];
            const float r3 = c2[reg];
            const float sj = sP[reg];
            const float r3s = r3 * sj;
            const float4 u = unit_lds[j];
            accs = fmaf(r1, sj, accs);
            av0 = fmaf(r3s, u.x, av0);
            av1 = fmaf(r3s, u.y, av1);
            av2 = fmaf(r3s, u.z, av2);
            if (LAYER > 0) {
                av0 = fmaf(r2, vP[reg].x, av0);
                av1 = fmaf(r2, vP[reg].y, av1);
                av2 = fmaf(r2, vP[reg].z, av2);
            }
        }
#pragma unroll
        for (int reg = 0; reg < 4; ++reg) {
            sP[reg] = sN[reg];
            if (LAYER > 0) vP[reg] = vN[reg];
        }
    }

    accs += __shfl_xor(accs, 16, 64); accs += __shfl_xor(accs, 32, 64);
    av0  += __shfl_xor(av0, 16, 64);  av0  += __shfl_xor(av0, 32, 64);
    av1  += __shfl_xor(av1, 16, 64);  av1  += __shfl_xor(av1, 32, 64);
    av2  += __shfl_xor(av2, 16, 64);  av2  += __shfl_xor(av2, 32, 64);
    if (l < 16) {
        // 1/127 already folded into W2 fragments; phi_pool dead -> agg4 alias OK
        ((float*)agg4)[0 * 64 + f] = accs;
        ((float*)agg4)[1 * 64 + f] = av0;
        ((float*)agg4)[2 * 64 + f] = av1;
        ((float*)agg4)[3 * 64 + f] = av2;
    }
    __syncthreads();

    // ---- tail: node update (+ readout for last layer), coalesced wT4 ------
    // wT4 layout: [m][ff4][g][4]; lane g loads float4 at (m*16+ff4)*64+g.
    const int g = l;
    const float4* wv4 = (const float4*)wT4;
    if (LAYER == 0) {
        const int m = (w == 0) ? 0 : 1;
        const int row = (w == 0) ? 0 : w;
        float a = (w == 0) ? s_in[node * FF + g] : 0.0f;
#pragma unroll
        for (int k = 0; k < 16; ++k) {
            const float4 w4 = wv4[(m * 16 + k) * 64 + g];
            const float4 a4 = agg4[row][k];
            a = fmaf(a4.x, w4.x, a); a = fmaf(a4.y, w4.y, a);
            a = fmaf(a4.z, w4.z, a); a = fmaf(a4.w, w4.w, a);
        }
        if (w == 0) s_out[node * FF + g] = a;
        else        v_out[(node * FF + g) * 4 + (w - 1)] = a;
    } else {
        if (w > 0) {
            const int d = w - 1;
            float a = v_in[(node * FF + g) * 4 + d];
#pragma unroll
            for (int k = 0; k < 16; ++k) {
                const float4 w4 = wv4[(16 + k) * 64 + g];
                const float4 a4 = agg4[w][k];
                a = fmaf(a4.x, w4.x, a); a = fmaf(a4.y, w4.y, a);
                a = fmaf(a4.z, w4.z, a); a = fmaf(a4.w, w4.w, a);
            }
            float p = a * wout[g];
#pragma unroll
            for (int off = 1; off < 64; off <<= 1)
                p += __shfl_xor(p, off, 64);
            if (l == 0)
                out[node * 3 + d] = (p - pos[node * 3 + d]) * scale[0];
        }
    }
}

extern "C" void kernel_launch(void* const* d_in, const int* in_sizes, int n_in,
                              void* d_out, int out_size, void* d_ws, size_t ws_size,
                              hipStream_t stream) {
    const float* pos     = (const float*)d_in[0];
    const int*   species = (const int*)  d_in[1];
    const float* glob    = (const float*)d_in[2];
    const float* embed   = (const float*)d_in[3];
    const float* glob_w  = (const float*)d_in[4];
    const float* rbf_w1  = (const float*)d_in[5];   // [2][8][64]
    const float* rbf_b1  = (const float*)d_in[6];   // [2][64]
    const float* rbf_w2  = (const float*)d_in[7];   // [2][64][192]
    const float* ws      = (const float*)d_in[8];   // [2][64][64]
    const float* wv      = (const float*)d_in[9];   // [2][64][64]
    const float* wout    = (const float*)d_in[10];  // [64]
    const float* scale   = (const float*)d_in[11];  // [1]

    float* wsf = (float*)d_ws;
    float* s0     = wsf;                        // 262144 floats
    float* s1     = wsf + 262144;               // 262144
    float* v1     = wsf + 524288;               // 1048576
    short* w2frag = (short*)(wsf + 1572864);    // 24576 shorts (12288 floats)
    float* wT4    = wsf + 1585152;              // 16384 floats
    _Float16* w1A = (_Float16*)(wsf + 1601536); // 2048 halfs (1024 floats)
    float* outp = (float*)d_out;

    setup_kernel<<<dim3(192 + BB * NN / 4), 256, 0, stream>>>(
        rbf_w2, ws, wv, rbf_w1, rbf_b1, species, glob, embed, glob_w,
        w2frag, wT4, w1A, s0);

    msg_kernel<0><<<dim3(NN * BB), 256, 0, stream>>>(
        pos, s0, nullptr,
        (const half4*)w1A, w2frag, wT4, wout, scale,
        s1, v1, nullptr);

    msg_kernel<1><<<dim3(NN * BB), 256, 0, stream>>>(
        pos, s1, v1,
        (const half4*)(w1A + 1024), w2frag + 12288, wT4 + 8192, wout, scale,
        nullptr, nullptr, outp);
}